// Round 8
// baseline (313.835 us; speedup 1.0000x reference)
//
#include <hip/hip_runtime.h>
#include <hip/hip_bf16.h>
#include <math.h>

#define NN 16384
#define DEG 20
#define EE (NN*DEG)
#define RMAXF 3.5f
#define NG 4   // edge-groups (of 16) per block

typedef __attribute__((ext_vector_type(8))) short short8;
typedef __attribute__((ext_vector_type(4))) float f32x4;

// soft_unit_step: exp(-1/x) for x>0 else 0
__device__ __forceinline__ float su_f(float x) {
    return x > 0.0f ? __expf(-1.0f / x) : 0.0f;
}
__device__ __forceinline__ ushort f2bf(float x) {
    __hip_bfloat16 h = __float2bfloat16(x);
    return *reinterpret_cast<ushort*>(&h);
}

// ---------------------------------------------------------------------------
// prep_kernel: blocks 0..15 pack W2 B-fragments (proven); blocks 16.. compute
// per-node logit vectors mq (proven round 6):
//   mq[n][j]       = sum_i qs_i * Wd_s[i][j]               (j<8)
//   mq[n][8+3j+c]  = (sum_i qv_i[c] * Wd_v[i][j]) / sqrt3
// ---------------------------------------------------------------------------
__global__ __launch_bounds__(256) void prep_kernel(
    const float* __restrict__ f, const float* __restrict__ Wqs,
    const float* __restrict__ Wqv, const float* __restrict__ Wk2,
    const float* __restrict__ Wv2, const float* __restrict__ Wds,
    const float* __restrict__ Wdv, uint4* __restrict__ wsB2,
    float* __restrict__ mq)
{
    if (blockIdx.x < 16) {
        int tid = blockIdx.x * 256 + threadIdx.x;
        int net = tid >> 11, s = (tid >> 10) & 1, tt = (tid >> 6) & 15, lane = tid & 63;
        int qq = lane >> 4, n = lane & 15, col = tt * 16 + n;
        const float* W2 = net ? Wv2 : Wk2;
        unsigned int r[4];
        #pragma unroll
        for (int jj = 0; jj < 4; jj++) {
            int k0 = s * 32 + qq * 8 + 2 * jj;
            unsigned int lo = f2bf(W2[k0 * 256 + col] * 0.125f);
            unsigned int hi = f2bf(W2[(k0 + 1) * 256 + col] * 0.125f);
            r[jj] = lo | (hi << 16);
        }
        wsB2[tid] = make_uint4(r[0], r[1], r[2], r[3]);
    } else {
        int gid = (blockIdx.x - 16) * 256 + threadIdx.x;
        int nn = gid >> 5, idx = gid & 31;
        const float* fr = f + (size_t)nn * 32;
        const float inv8 = 0.35355339059327373f; // 1/sqrt(8)
        float out = 0.0f;
        if (idx < 8) {
            int j = idx;
            #pragma unroll
            for (int i = 0; i < 8; i++) {
                float qs = 0.0f;
                #pragma unroll
                for (int a = 0; a < 8; a++) qs = fmaf(fr[a], Wqs[a * 8 + i], qs);
                out = fmaf(qs * inv8, Wds[i * 8 + j], out);
            }
        } else {
            int kk = idx - 8;
            int j = kk / 3, c = kk - 3 * j;
            #pragma unroll
            for (int i = 0; i < 8; i++) {
                float qv = 0.0f;
                #pragma unroll
                for (int a = 0; a < 8; a++) qv = fmaf(fr[8 + 3 * a + c], Wqv[a * 8 + i], qv);
                out = fmaf(qv * inv8, Wdv[i * 8 + j], out);
            }
            out *= 0.5773502691896258f; // 1/sqrt(3)
        }
        mq[(size_t)nn * 32 + idx] = out;
    }
}

// ---------------------------------------------------------------------------
// edge_kernel: round-6 math verbatim; occupancy restructure:
//  - single-net s_w[16][261] (16.7 KB), nets processed C0-D0-C1-D1
//  - single-net breg (32 VGPR), next net's fragments loaded right after the
//    current net's MFMAs (in-flight across >=1 phase, short liveness)
//  - s_g/s_mq padded to stride 33 (conflict-free phase-D reads)
//  LDS ~25.9 KB; target ~5 blocks/CU (20 waves) vs round-6's 3 (12 waves).
// ---------------------------------------------------------------------------
__global__ __launch_bounds__(256, 4) void edge_kernel(
    const float* __restrict__ f,   const float* __restrict__ pos,
    const float* __restrict__ Wk1, const float* __restrict__ Wv1,
    const int* __restrict__ esrc,  const int* __restrict__ edst,
    const float* __restrict__ mq,  const uint4* __restrict__ wsB2,
    float* __restrict__ logits, float* __restrict__ cutoff,
    float* __restrict__ vout)
{
    __shared__ float  s_w[16][261];                   // 16.7 KB, one net's D matrix
    __shared__ __align__(16) ushort s_hb[2][16][64];  // 4 KB bf16 h, XOR-swizzled
    __shared__ float s_g[16][33];                     // 2.1 KB, f[src], pad 33
    __shared__ float s_mq[16][33];                    // 2.1 KB, mq[dst], pad 33
    __shared__ float s_emb[16][10];
    __shared__ float s_s1[16][4];

    const int t = threadIdx.x;
    const int wave = t >> 6, lane = t & 63;
    const int qd = lane >> 4, n = lane & 15;

    // ---- B fragments: one net at a time (32 VGPR). Start with net 0. ----
    short8 bcur[2][4]; // [kstep][jj]
    #pragma unroll
    for (int s = 0; s < 2; s++)
        #pragma unroll
        for (int jj = 0; jj < 4; jj++)
            bcur[s][jj] = *(const short8*)&wsB2[s * 1024 + (wave * 4 + jj) * 64 + lane];

    for (int g = 0; g < NG; g++) {
        const int e0 = (blockIdx.x * NG + g) * 16;

        // ---- phase A: geometry + radial basis (threads 0..15) ----
        if (t < 16) {
            int e = e0 + t;
            int s = esrc[e], d = edst[e];
            float vx = pos[s * 3 + 0] - pos[d * 3 + 0];
            float vy = pos[s * 3 + 1] - pos[d * 3 + 1];
            float vz = pos[s * 3 + 2] - pos[d * 3 + 2];
            float r = sqrtf(vx * vx + vy * vy + vz * vz);
            float invr = 1.0f / r;
            const float sqrt3 = 1.7320508075688772f;
            s_s1[t][0] = sqrt3 * vx * invr;
            s_s1[t][1] = sqrt3 * vy * invr;
            s_s1[t][2] = sqrt3 * vz * invr;
            cutoff[e] = su_f(10.0f * (1.0f - r / RMAXF));
            const float step = RMAXF / 11.0f;
            const float invstep = 11.0f / RMAXF;
            const float K = 26.66929988626f; // 1.14136*e^2*sqrt(10)
            #pragma unroll
            for (int j = 0; j < 10; j++) {
                float dd = (r - step * (float)(j + 1)) * invstep;
                s_emb[t][j] = K * su_f(dd + 1.0f) * su_f(1.0f - dd);
            }
        }
        // ---- phase A2: stage gathered f[src] and mq[dst] rows ----
        {
            int el = t >> 4, j = t & 15;
            int e = e0 + el;
            int s = esrc[e], d = edst[e];
            s_g[el][j]       = f[(size_t)s * 32 + j];
            s_g[el][16 + j]  = f[(size_t)s * 32 + 16 + j];
            s_mq[el][j]      = mq[(size_t)d * 32 + j];
            s_mq[el][16 + j] = mq[(size_t)d * 32 + 16 + j];
        }
        __syncthreads(); // barrier 1

        // ---- phase B: scalar GEMM1 + silu (both nets) -> s_hb ----
        {
            const float invsq10 = 0.31622776601683794f; // 1/sqrt(10)
            #pragma unroll
            for (int e = 0; e < 4; e++) {
                int el = wave * 4 + e;
                float ak = 0.0f, av = 0.0f;
                #pragma unroll
                for (int j = 0; j < 10; j++) {
                    float ej = s_emb[el][j];
                    ak = fmaf(ej, Wk1[j * 64 + lane], ak);
                    av = fmaf(ej, Wv1[j * 64 + lane], av);
                }
                ak *= invsq10; av *= invsq10;
                float hk = ak / (1.0f + __expf(-ak));
                float hv = av / (1.0f + __expf(-av));
                int pos_ = ((((lane >> 3) ^ (el & 7))) << 3) | (lane & 7);
                s_hb[0][el][pos_] = f2bf(hk);
                s_hb[1][el][pos_] = f2bf(hv);
            }
        }
        __syncthreads(); // barrier 2

        // ---- phase C0: k-net MFMA -> s_w; then start net-1 B loads ----
        {
            short8 ha0 = *(const short8*)&s_hb[0][n][((qd ^ (n & 7)) << 3)];
            short8 ha1 = *(const short8*)&s_hb[0][n][(((4 + qd) ^ (n & 7)) << 3)];
            #pragma unroll
            for (int jj = 0; jj < 4; jj++) {
                int tt = wave * 4 + jj;
                f32x4 d = {0.0f, 0.0f, 0.0f, 0.0f};
                d = __builtin_amdgcn_mfma_f32_16x16x32_bf16(ha0, bcur[0][jj], d, 0, 0, 0);
                d = __builtin_amdgcn_mfma_f32_16x16x32_bf16(ha1, bcur[1][jj], d, 0, 0, 0);
                #pragma unroll
                for (int r = 0; r < 4; r++)
                    s_w[4 * qd + r][tt * 16 + n] = d[r]; // D: row=4*quad+reg, col=n
            }
            // prefetch v-net B fragments (consumed in C1, >=1 phase away)
            #pragma unroll
            for (int s = 0; s < 2; s++)
                #pragma unroll
                for (int jj = 0; jj < 4; jj++)
                    bcur[s][jj] = *(const short8*)&wsB2[2048 + s * 1024 +
                                                        (wave * 4 + jj) * 64 + lane];
        }
        __syncthreads(); // barrier 3

        // ---- phase D0: k-net TP + mq-logits (round-6 math) ----
        {
            int el = t >> 4, role = t & 15;
            int e = e0 + el;
            float s1x = s_s1[el][0], s1y = s_s1[el][1], s1z = s_s1[el][2];
            const float inv_sqrt3 = 0.5773502691896258f;
            float a[8], b[8];
            #pragma unroll
            for (int i = 0; i < 8; i++) {
                a[i] = s_g[el][i];
                b[i] = (s_g[el][8 + i * 3 + 0] * s1x +
                        s_g[el][8 + i * 3 + 1] * s1y +
                        s_g[el][8 + i * 3 + 2] * s1z) * inv_sqrt3;
            }
            const float nrm = 0.25f; // 1/(sqrt(8)*sqrt(2))
            const float* wk = s_w[el];
            float contrib = 0.0f;
            if (role < 8) {
                int o = role;
                float ks = 0.0f;
                #pragma unroll
                for (int i = 0; i < 8; i++)
                    ks += a[i] * wk[i * 8 + o] + b[i] * wk[64 + i * 8 + o];
                contrib = s_mq[el][o] * (ks * nrm);
            } else {
                int o = role - 8;
                #pragma unroll
                for (int c = 0; c < 3; c++) {
                    float uk = 0.0f, tk = 0.0f;
                    #pragma unroll
                    for (int i = 0; i < 8; i++) {
                        uk += a[i] * wk[128 + i * 8 + o];
                        tk = fmaf(s_g[el][8 + i * 3 + c], wk[192 + i * 8 + o], tk);
                    }
                    float kv_c = nrm * (s_s1[el][c] * uk + tk);
                    contrib = fmaf(s_mq[el][8 + 3 * o + c], kv_c, contrib);
                }
            }
            contrib += __shfl_xor(contrib, 1);
            contrib += __shfl_xor(contrib, 2);
            contrib += __shfl_xor(contrib, 4);
            contrib += __shfl_xor(contrib, 8);
            if (role == 0) logits[e] = contrib * 0.08838834764831845f; // 1/(8*sqrt(2))
        }
        __syncthreads(); // barrier 4

        // ---- phase C1: v-net MFMA -> s_w; then start net-0 loads (next g) ----
        {
            short8 ha0 = *(const short8*)&s_hb[1][n][((qd ^ (n & 7)) << 3)];
            short8 ha1 = *(const short8*)&s_hb[1][n][(((4 + qd) ^ (n & 7)) << 3)];
            #pragma unroll
            for (int jj = 0; jj < 4; jj++) {
                int tt = wave * 4 + jj;
                f32x4 d = {0.0f, 0.0f, 0.0f, 0.0f};
                d = __builtin_amdgcn_mfma_f32_16x16x32_bf16(ha0, bcur[0][jj], d, 0, 0, 0);
                d = __builtin_amdgcn_mfma_f32_16x16x32_bf16(ha1, bcur[1][jj], d, 0, 0, 0);
                #pragma unroll
                for (int r = 0; r < 4; r++)
                    s_w[4 * qd + r][tt * 16 + n] = d[r];
            }
            // prefetch k-net B fragments for the next group
            #pragma unroll
            for (int s = 0; s < 2; s++)
                #pragma unroll
                for (int jj = 0; jj < 4; jj++)
                    bcur[s][jj] = *(const short8*)&wsB2[s * 1024 +
                                                        (wave * 4 + jj) * 64 + lane];
        }
        __syncthreads(); // barrier 5

        // ---- phase D1: v-net TP -> vout (round-6 math, a/b recomputed) ----
        {
            int el = t >> 4, role = t & 15;
            int e = e0 + el;
            float s1x = s_s1[el][0], s1y = s_s1[el][1], s1z = s_s1[el][2];
            const float inv_sqrt3 = 0.5773502691896258f;
            float a[8], b[8];
            #pragma unroll
            for (int i = 0; i < 8; i++) {
                a[i] = s_g[el][i];
                b[i] = (s_g[el][8 + i * 3 + 0] * s1x +
                        s_g[el][8 + i * 3 + 1] * s1y +
                        s_g[el][8 + i * 3 + 2] * s1z) * inv_sqrt3;
            }
            const float nrm = 0.25f;
            const float* wv = s_w[el];
            if (role < 8) {
                int o = role;
                float vs = 0.0f;
                #pragma unroll
                for (int i = 0; i < 8; i++)
                    vs += a[i] * wv[i * 8 + o] + b[i] * wv[64 + i * 8 + o];
                vout[(size_t)e * 32 + o] = vs * nrm;
            } else {
                int o = role - 8;
                #pragma unroll
                for (int c = 0; c < 3; c++) {
                    float uv = 0.0f, tv = 0.0f;
                    #pragma unroll
                    for (int i = 0; i < 8; i++) {
                        uv += a[i] * wv[128 + i * 8 + o];
                        tv = fmaf(s_g[el][8 + i * 3 + c], wv[192 + i * 8 + o], tv);
                    }
                    vout[(size_t)e * 32 + 8 + o * 3 + c] = nrm * (s_s1[el][c] * uv + tv);
                }
            }
        }
        __syncthreads(); // barrier 6: protect s_* before next group's phase A
    }
}

// ---------------------------------------------------------------------------
// out_kernel: one half-wave (32 lanes) per node (proven, fp32 v).
// ---------------------------------------------------------------------------
__global__ __launch_bounds__(256) void out_kernel(
    const float* __restrict__ logits, const float* __restrict__ cutoff,
    const float* __restrict__ v, float* __restrict__ out)
{
    int t = threadIdx.x, wave = t >> 6, lane = t & 63;
    int half = lane >> 5, hl = lane & 31;
    int n = blockIdx.x * 8 + wave * 2 + half;

    float lg = -INFINITY, cw = 0.0f;
    if (hl < DEG) {
        lg = logits[(size_t)n * DEG + hl];
        cw = cutoff[(size_t)n * DEG + hl];
    }
    float mx = lg;
    mx = fmaxf(mx, __shfl_xor(mx, 16));
    mx = fmaxf(mx, __shfl_xor(mx, 8));
    mx = fmaxf(mx, __shfl_xor(mx, 4));
    mx = fmaxf(mx, __shfl_xor(mx, 2));
    mx = fmaxf(mx, __shfl_xor(mx, 1));

    float ew = cw * __expf(lg - mx);
    float z = ew;
    z += __shfl_xor(z, 16);
    z += __shfl_xor(z, 8);
    z += __shfl_xor(z, 4);
    z += __shfl_xor(z, 2);
    z += __shfl_xor(z, 1);
    z = (z == 0.0f) ? 1.0f : z;
    float coef = sqrtf(ew / z + 1e-12f);

    float acc = 0.0f;
    int base = half * 32;
    #pragma unroll
    for (int ee = 0; ee < DEG; ee++) {
        float ce = __shfl(coef, base + ee);
        acc = fmaf(ce, v[((size_t)n * DEG + ee) * 32 + hl], acc);
    }
    out[(size_t)n * 32 + hl] = acc;
}

// ---------------------------------------------------------------------------
extern "C" void kernel_launch(void* const* d_in, const int* in_sizes, int n_in,
                              void* d_out, int out_size, void* d_ws, size_t ws_size,
                              hipStream_t stream) {
    const float* f    = (const float*)d_in[0];
    const float* pos  = (const float*)d_in[1];
    const float* Wqs  = (const float*)d_in[2];
    const float* Wqv  = (const float*)d_in[3];
    const float* Wk1  = (const float*)d_in[4];
    const float* Wk2  = (const float*)d_in[5];
    const float* Wv1  = (const float*)d_in[6];
    const float* Wv2  = (const float*)d_in[7];
    const float* Wds  = (const float*)d_in[8];
    const float* Wdv  = (const float*)d_in[9];
    const int* esrc   = (const int*)d_in[10];
    const int* edst   = (const int*)d_in[11];
    float* out        = (float*)d_out;

    char* ws = (char*)d_ws;
    uint4* wsB2  = (uint4*)(ws);                       // 65536 B
    float* mqbuf = (float*)(ws + 65536);               // N*32*4 = 2 MB
    float* lbuf  = mqbuf + (size_t)NN * 32;            // E
    float* cbuf  = lbuf + (size_t)EE;                  // E
    float* vbuf  = cbuf + (size_t)EE;                  // E*32

    prep_kernel<<<dim3(16 + (NN * 32) / 256), dim3(256), 0, stream>>>(
        f, Wqs, Wqv, Wk2, Wv2, Wds, Wdv, wsB2, mqbuf);
    edge_kernel<<<dim3(EE / (16 * NG)), dim3(256), 0, stream>>>(
        f, pos, Wk1, Wv1, esrc, edst, mqbuf, wsB2, lbuf, cbuf, vbuf);
    out_kernel<<<dim3(NN / 8), dim3(256), 0, stream>>>(lbuf, cbuf, vbuf, out);
}

// Round 9
// 258.995 us; speedup vs baseline: 1.2117x; 1.2117x over previous
//
#include <hip/hip_runtime.h>
#include <hip/hip_bf16.h>
#include <math.h>

#define NN 16384
#define DEG 20
#define EE (NN*DEG)
#define RMAXF 3.5f
#define NG 4   // edge-groups (of 16) per block

typedef __attribute__((ext_vector_type(8))) short short8;
typedef __attribute__((ext_vector_type(4))) float f32x4;

// soft_unit_step: exp(-1/x) for x>0 else 0
__device__ __forceinline__ float su_f(float x) {
    return x > 0.0f ? __expf(-1.0f / x) : 0.0f;
}
__device__ __forceinline__ ushort f2bf(float x) {
    __hip_bfloat16 h = __float2bfloat16(x);
    return *reinterpret_cast<ushort*>(&h);
}

// ---------------------------------------------------------------------------
// prep_kernel: blocks 0..15 pack W2 B-fragments (proven); blocks 16.. compute
// per-node logit vectors mq (proven round 6):
//   mq[n][j]       = sum_i qs_i * Wd_s[i][j]               (j<8)
//   mq[n][8+3j+c]  = (sum_i qv_i[c] * Wd_v[i][j]) / sqrt3
// ---------------------------------------------------------------------------
__global__ __launch_bounds__(256) void prep_kernel(
    const float* __restrict__ f, const float* __restrict__ Wqs,
    const float* __restrict__ Wqv, const float* __restrict__ Wk2,
    const float* __restrict__ Wv2, const float* __restrict__ Wds,
    const float* __restrict__ Wdv, uint4* __restrict__ wsB2,
    float* __restrict__ mq)
{
    if (blockIdx.x < 16) {
        int tid = blockIdx.x * 256 + threadIdx.x;
        int net = tid >> 11, s = (tid >> 10) & 1, tt = (tid >> 6) & 15, lane = tid & 63;
        int qq = lane >> 4, n = lane & 15, col = tt * 16 + n;
        const float* W2 = net ? Wv2 : Wk2;
        unsigned int r[4];
        #pragma unroll
        for (int jj = 0; jj < 4; jj++) {
            int k0 = s * 32 + qq * 8 + 2 * jj;
            unsigned int lo = f2bf(W2[k0 * 256 + col] * 0.125f);
            unsigned int hi = f2bf(W2[(k0 + 1) * 256 + col] * 0.125f);
            r[jj] = lo | (hi << 16);
        }
        wsB2[tid] = make_uint4(r[0], r[1], r[2], r[3]);
    } else {
        int gid = (blockIdx.x - 16) * 256 + threadIdx.x;
        int nn = gid >> 5, idx = gid & 31;
        const float* fr = f + (size_t)nn * 32;
        const float inv8 = 0.35355339059327373f; // 1/sqrt(8)
        float out = 0.0f;
        if (idx < 8) {
            int j = idx;
            #pragma unroll
            for (int i = 0; i < 8; i++) {
                float qs = 0.0f;
                #pragma unroll
                for (int a = 0; a < 8; a++) qs = fmaf(fr[a], Wqs[a * 8 + i], qs);
                out = fmaf(qs * inv8, Wds[i * 8 + j], out);
            }
        } else {
            int kk = idx - 8;
            int j = kk / 3, c = kk - 3 * j;
            #pragma unroll
            for (int i = 0; i < 8; i++) {
                float qv = 0.0f;
                #pragma unroll
                for (int a = 0; a < 8; a++) qv = fmaf(fr[8 + 3 * a + c], Wqv[a * 8 + i], qv);
                out = fmaf(qv * inv8, Wdv[i * 8 + j], out);
            }
            out *= 0.5773502691896258f; // 1/sqrt(3)
        }
        mq[(size_t)nn * 32 + idx] = out;
    }
}

// ---------------------------------------------------------------------------
// edge_kernel: round-8 structure verbatim (single-net s_w + single-net bcur,
// LDS ~26 KB) with the ONE change: __launch_bounds__(256,3) so the register
// allocator has ~170 regs/thread and does not spill (round-8's (256,4)
// forced VGPR=64 -> 520 MB of scratch traffic).
// ---------------------------------------------------------------------------
__global__ __launch_bounds__(256, 3) void edge_kernel(
    const float* __restrict__ f,   const float* __restrict__ pos,
    const float* __restrict__ Wk1, const float* __restrict__ Wv1,
    const int* __restrict__ esrc,  const int* __restrict__ edst,
    const float* __restrict__ mq,  const uint4* __restrict__ wsB2,
    float* __restrict__ logits, float* __restrict__ cutoff,
    float* __restrict__ vout)
{
    __shared__ float  s_w[16][261];                   // 16.7 KB, one net's D matrix
    __shared__ __align__(16) ushort s_hb[2][16][64];  // 4 KB bf16 h, XOR-swizzled
    __shared__ float s_g[16][33];                     // 2.1 KB, f[src], pad 33
    __shared__ float s_mq[16][33];                    // 2.1 KB, mq[dst], pad 33
    __shared__ float s_emb[16][10];
    __shared__ float s_s1[16][4];

    const int t = threadIdx.x;
    const int wave = t >> 6, lane = t & 63;
    const int qd = lane >> 4, n = lane & 15;

    // ---- B fragments: one net at a time (32 VGPR). Start with net 0. ----
    short8 bcur[2][4]; // [kstep][jj]
    #pragma unroll
    for (int s = 0; s < 2; s++)
        #pragma unroll
        for (int jj = 0; jj < 4; jj++)
            bcur[s][jj] = *(const short8*)&wsB2[s * 1024 + (wave * 4 + jj) * 64 + lane];

    for (int g = 0; g < NG; g++) {
        const int e0 = (blockIdx.x * NG + g) * 16;

        // ---- phase A: geometry + radial basis (threads 0..15) ----
        if (t < 16) {
            int e = e0 + t;
            int s = esrc[e], d = edst[e];
            float vx = pos[s * 3 + 0] - pos[d * 3 + 0];
            float vy = pos[s * 3 + 1] - pos[d * 3 + 1];
            float vz = pos[s * 3 + 2] - pos[d * 3 + 2];
            float r = sqrtf(vx * vx + vy * vy + vz * vz);
            float invr = 1.0f / r;
            const float sqrt3 = 1.7320508075688772f;
            s_s1[t][0] = sqrt3 * vx * invr;
            s_s1[t][1] = sqrt3 * vy * invr;
            s_s1[t][2] = sqrt3 * vz * invr;
            cutoff[e] = su_f(10.0f * (1.0f - r / RMAXF));
            const float step = RMAXF / 11.0f;
            const float invstep = 11.0f / RMAXF;
            const float K = 26.66929988626f; // 1.14136*e^2*sqrt(10)
            #pragma unroll
            for (int j = 0; j < 10; j++) {
                float dd = (r - step * (float)(j + 1)) * invstep;
                s_emb[t][j] = K * su_f(dd + 1.0f) * su_f(1.0f - dd);
            }
        }
        // ---- phase A2: stage gathered f[src] and mq[dst] rows ----
        {
            int el = t >> 4, j = t & 15;
            int e = e0 + el;
            int s = esrc[e], d = edst[e];
            s_g[el][j]       = f[(size_t)s * 32 + j];
            s_g[el][16 + j]  = f[(size_t)s * 32 + 16 + j];
            s_mq[el][j]      = mq[(size_t)d * 32 + j];
            s_mq[el][16 + j] = mq[(size_t)d * 32 + 16 + j];
        }
        __syncthreads(); // barrier 1

        // ---- phase B: scalar GEMM1 + silu (both nets) -> s_hb ----
        {
            const float invsq10 = 0.31622776601683794f; // 1/sqrt(10)
            #pragma unroll
            for (int e = 0; e < 4; e++) {
                int el = wave * 4 + e;
                float ak = 0.0f, av = 0.0f;
                #pragma unroll
                for (int j = 0; j < 10; j++) {
                    float ej = s_emb[el][j];
                    ak = fmaf(ej, Wk1[j * 64 + lane], ak);
                    av = fmaf(ej, Wv1[j * 64 + lane], av);
                }
                ak *= invsq10; av *= invsq10;
                float hk = ak / (1.0f + __expf(-ak));
                float hv = av / (1.0f + __expf(-av));
                int pos_ = ((((lane >> 3) ^ (el & 7))) << 3) | (lane & 7);
                s_hb[0][el][pos_] = f2bf(hk);
                s_hb[1][el][pos_] = f2bf(hv);
            }
        }
        __syncthreads(); // barrier 2

        // ---- phase C0: k-net MFMA -> s_w; then start net-1 B loads ----
        {
            short8 ha0 = *(const short8*)&s_hb[0][n][((qd ^ (n & 7)) << 3)];
            short8 ha1 = *(const short8*)&s_hb[0][n][(((4 + qd) ^ (n & 7)) << 3)];
            #pragma unroll
            for (int jj = 0; jj < 4; jj++) {
                int tt = wave * 4 + jj;
                f32x4 d = {0.0f, 0.0f, 0.0f, 0.0f};
                d = __builtin_amdgcn_mfma_f32_16x16x32_bf16(ha0, bcur[0][jj], d, 0, 0, 0);
                d = __builtin_amdgcn_mfma_f32_16x16x32_bf16(ha1, bcur[1][jj], d, 0, 0, 0);
                #pragma unroll
                for (int r = 0; r < 4; r++)
                    s_w[4 * qd + r][tt * 16 + n] = d[r]; // D: row=4*quad+reg, col=n
            }
            // prefetch v-net B fragments (consumed in C1, >=1 phase away)
            #pragma unroll
            for (int s = 0; s < 2; s++)
                #pragma unroll
                for (int jj = 0; jj < 4; jj++)
                    bcur[s][jj] = *(const short8*)&wsB2[2048 + s * 1024 +
                                                        (wave * 4 + jj) * 64 + lane];
        }
        __syncthreads(); // barrier 3

        // ---- phase D0: k-net TP + mq-logits (round-6 math) ----
        {
            int el = t >> 4, role = t & 15;
            int e = e0 + el;
            float s1x = s_s1[el][0], s1y = s_s1[el][1], s1z = s_s1[el][2];
            const float inv_sqrt3 = 0.5773502691896258f;
            float a[8], b[8];
            #pragma unroll
            for (int i = 0; i < 8; i++) {
                a[i] = s_g[el][i];
                b[i] = (s_g[el][8 + i * 3 + 0] * s1x +
                        s_g[el][8 + i * 3 + 1] * s1y +
                        s_g[el][8 + i * 3 + 2] * s1z) * inv_sqrt3;
            }
            const float nrm = 0.25f; // 1/(sqrt(8)*sqrt(2))
            const float* wk = s_w[el];
            float contrib = 0.0f;
            if (role < 8) {
                int o = role;
                float ks = 0.0f;
                #pragma unroll
                for (int i = 0; i < 8; i++)
                    ks += a[i] * wk[i * 8 + o] + b[i] * wk[64 + i * 8 + o];
                contrib = s_mq[el][o] * (ks * nrm);
            } else {
                int o = role - 8;
                #pragma unroll
                for (int c = 0; c < 3; c++) {
                    float uk = 0.0f, tk = 0.0f;
                    #pragma unroll
                    for (int i = 0; i < 8; i++) {
                        uk += a[i] * wk[128 + i * 8 + o];
                        tk = fmaf(s_g[el][8 + i * 3 + c], wk[192 + i * 8 + o], tk);
                    }
                    float kv_c = nrm * (s_s1[el][c] * uk + tk);
                    contrib = fmaf(s_mq[el][8 + 3 * o + c], kv_c, contrib);
                }
            }
            contrib += __shfl_xor(contrib, 1);
            contrib += __shfl_xor(contrib, 2);
            contrib += __shfl_xor(contrib, 4);
            contrib += __shfl_xor(contrib, 8);
            if (role == 0) logits[e] = contrib * 0.08838834764831845f; // 1/(8*sqrt(2))
        }
        __syncthreads(); // barrier 4

        // ---- phase C1: v-net MFMA -> s_w; then start net-0 loads (next g) ----
        {
            short8 ha0 = *(const short8*)&s_hb[1][n][((qd ^ (n & 7)) << 3)];
            short8 ha1 = *(const short8*)&s_hb[1][n][(((4 + qd) ^ (n & 7)) << 3)];
            #pragma unroll
            for (int jj = 0; jj < 4; jj++) {
                int tt = wave * 4 + jj;
                f32x4 d = {0.0f, 0.0f, 0.0f, 0.0f};
                d = __builtin_amdgcn_mfma_f32_16x16x32_bf16(ha0, bcur[0][jj], d, 0, 0, 0);
                d = __builtin_amdgcn_mfma_f32_16x16x32_bf16(ha1, bcur[1][jj], d, 0, 0, 0);
                #pragma unroll
                for (int r = 0; r < 4; r++)
                    s_w[4 * qd + r][tt * 16 + n] = d[r];
            }
            // prefetch k-net B fragments for the next group
            #pragma unroll
            for (int s = 0; s < 2; s++)
                #pragma unroll
                for (int jj = 0; jj < 4; jj++)
                    bcur[s][jj] = *(const short8*)&wsB2[s * 1024 +
                                                        (wave * 4 + jj) * 64 + lane];
        }
        __syncthreads(); // barrier 5

        // ---- phase D1: v-net TP -> vout (round-6 math, a/b recomputed) ----
        {
            int el = t >> 4, role = t & 15;
            int e = e0 + el;
            float s1x = s_s1[el][0], s1y = s_s1[el][1], s1z = s_s1[el][2];
            const float inv_sqrt3 = 0.5773502691896258f;
            float a[8], b[8];
            #pragma unroll
            for (int i = 0; i < 8; i++) {
                a[i] = s_g[el][i];
                b[i] = (s_g[el][8 + i * 3 + 0] * s1x +
                        s_g[el][8 + i * 3 + 1] * s1y +
                        s_g[el][8 + i * 3 + 2] * s1z) * inv_sqrt3;
            }
            const float nrm = 0.25f;
            const float* wv = s_w[el];
            if (role < 8) {
                int o = role;
                float vs = 0.0f;
                #pragma unroll
                for (int i = 0; i < 8; i++)
                    vs += a[i] * wv[i * 8 + o] + b[i] * wv[64 + i * 8 + o];
                vout[(size_t)e * 32 + o] = vs * nrm;
            } else {
                int o = role - 8;
                #pragma unroll
                for (int c = 0; c < 3; c++) {
                    float uv = 0.0f, tv = 0.0f;
                    #pragma unroll
                    for (int i = 0; i < 8; i++) {
                        uv += a[i] * wv[128 + i * 8 + o];
                        tv = fmaf(s_g[el][8 + i * 3 + c], wv[192 + i * 8 + o], tv);
                    }
                    vout[(size_t)e * 32 + 8 + o * 3 + c] = nrm * (s_s1[el][c] * uv + tv);
                }
            }
        }
        __syncthreads(); // barrier 6: protect s_* before next group's phase A
    }
}

// ---------------------------------------------------------------------------
// out_kernel: one half-wave (32 lanes) per node (proven, fp32 v).
// ---------------------------------------------------------------------------
__global__ __launch_bounds__(256) void out_kernel(
    const float* __restrict__ logits, const float* __restrict__ cutoff,
    const float* __restrict__ v, float* __restrict__ out)
{
    int t = threadIdx.x, wave = t >> 6, lane = t & 63;
    int half = lane >> 5, hl = lane & 31;
    int n = blockIdx.x * 8 + wave * 2 + half;

    float lg = -INFINITY, cw = 0.0f;
    if (hl < DEG) {
        lg = logits[(size_t)n * DEG + hl];
        cw = cutoff[(size_t)n * DEG + hl];
    }
    float mx = lg;
    mx = fmaxf(mx, __shfl_xor(mx, 16));
    mx = fmaxf(mx, __shfl_xor(mx, 8));
    mx = fmaxf(mx, __shfl_xor(mx, 4));
    mx = fmaxf(mx, __shfl_xor(mx, 2));
    mx = fmaxf(mx, __shfl_xor(mx, 1));

    float ew = cw * __expf(lg - mx);
    float z = ew;
    z += __shfl_xor(z, 16);
    z += __shfl_xor(z, 8);
    z += __shfl_xor(z, 4);
    z += __shfl_xor(z, 2);
    z += __shfl_xor(z, 1);
    z = (z == 0.0f) ? 1.0f : z;
    float coef = sqrtf(ew / z + 1e-12f);

    float acc = 0.0f;
    int base = half * 32;
    #pragma unroll
    for (int ee = 0; ee < DEG; ee++) {
        float ce = __shfl(coef, base + ee);
        acc = fmaf(ce, v[((size_t)n * DEG + ee) * 32 + hl], acc);
    }
    out[(size_t)n * 32 + hl] = acc;
}

// ---------------------------------------------------------------------------
extern "C" void kernel_launch(void* const* d_in, const int* in_sizes, int n_in,
                              void* d_out, int out_size, void* d_ws, size_t ws_size,
                              hipStream_t stream) {
    const float* f    = (const float*)d_in[0];
    const float* pos  = (const float*)d_in[1];
    const float* Wqs  = (const float*)d_in[2];
    const float* Wqv  = (const float*)d_in[3];
    const float* Wk1  = (const float*)d_in[4];
    const float* Wk2  = (const float*)d_in[5];
    const float* Wv1  = (const float*)d_in[6];
    const float* Wv2  = (const float*)d_in[7];
    const float* Wds  = (const float*)d_in[8];
    const float* Wdv  = (const float*)d_in[9];
    const int* esrc   = (const int*)d_in[10];
    const int* edst   = (const int*)d_in[11];
    float* out        = (float*)d_out;

    char* ws = (char*)d_ws;
    uint4* wsB2  = (uint4*)(ws);                       // 65536 B
    float* mqbuf = (float*)(ws + 65536);               // N*32*4 = 2 MB
    float* lbuf  = mqbuf + (size_t)NN * 32;            // E
    float* cbuf  = lbuf + (size_t)EE;                  // E
    float* vbuf  = cbuf + (size_t)EE;                  // E*32

    prep_kernel<<<dim3(16 + (NN * 32) / 256), dim3(256), 0, stream>>>(
        f, Wqs, Wqv, Wk2, Wv2, Wds, Wdv, wsB2, mqbuf);
    edge_kernel<<<dim3(EE / (16 * NG)), dim3(256), 0, stream>>>(
        f, pos, Wk1, Wv1, esrc, edst, mqbuf, wsB2, lbuf, cbuf, vbuf);
    out_kernel<<<dim3(NN / 8), dim3(256), 0, stream>>>(lbuf, cbuf, vbuf, out);
}

// Round 10
// 253.525 us; speedup vs baseline: 1.2379x; 1.0216x over previous
//
#include <hip/hip_runtime.h>
#include <hip/hip_bf16.h>
#include <math.h>

#define NN 16384
#define DEG 20
#define EE (NN*DEG)
#define RMAXF 3.5f
#define NGRP 5   // groups of 16 edges per block (80 edges = 4 nodes)

typedef __attribute__((ext_vector_type(8))) short short8;
typedef __attribute__((ext_vector_type(4))) float f32x4;

// soft_unit_step: exp(-1/x) for x>0 else 0
__device__ __forceinline__ float su_f(float x) {
    return x > 0.0f ? __expf(-1.0f / x) : 0.0f;
}
__device__ __forceinline__ ushort f2bf(float x) {
    __hip_bfloat16 h = __float2bfloat16(x);
    return *reinterpret_cast<ushort*>(&h);
}

// ---------------------------------------------------------------------------
// pack_kernel: W2 -> bf16 MFMA B-fragments (proven). Scale 1/8.
// B-frag lane(q=lane>>4, n=lane&15): 8 bf16 = W2[k=s*32+q*8+j][col=tt*16+n]
// wsB2 layout: [net][kstep s][tile tt (16)][lane (64)] as uint4.
// ---------------------------------------------------------------------------
__global__ __launch_bounds__(256) void pack_kernel(
    const float* __restrict__ Wk2, const float* __restrict__ Wv2,
    uint4* __restrict__ wsB2)
{
    int tid = blockIdx.x * 256 + threadIdx.x;
    int net = tid >> 11, s = (tid >> 10) & 1, tt = (tid >> 6) & 15, lane = tid & 63;
    int qq = lane >> 4, n = lane & 15, col = tt * 16 + n;
    const float* W2 = net ? Wv2 : Wk2;
    unsigned int r[4];
    #pragma unroll
    for (int jj = 0; jj < 4; jj++) {
        int k0 = s * 32 + qq * 8 + 2 * jj;
        unsigned int lo = f2bf(W2[k0 * 256 + col] * 0.125f);
        unsigned int hi = f2bf(W2[(k0 + 1) * 256 + col] * 0.125f);
        r[jj] = lo | (hi << 16);
    }
    wsB2[tid] = make_uint4(r[0], r[1], r[2], r[3]);
}

// ---------------------------------------------------------------------------
// edge_kernel: block = 256 threads = 4 waves; owns 4 whole nodes (80 edges,
// 5 groups of 16). Round-9 group machinery verbatim; logits/cutoff/v stay in
// LDS; softmax epilogue fused (proven out_kernel math); mq for the block's
// 4 dst nodes computed in prologue (verbatim prep math).
// Relies on edst[e] == e/20 (contiguous segments; exploited since round 1).
// ---------------------------------------------------------------------------
__global__ __launch_bounds__(256, 3) void edge_kernel(
    const float* __restrict__ f,   const float* __restrict__ pos,
    const float* __restrict__ Wqs, const float* __restrict__ Wqv,
    const float* __restrict__ Wds, const float* __restrict__ Wdv,
    const float* __restrict__ Wk1, const float* __restrict__ Wv1,
    const int* __restrict__ esrc,  const uint4* __restrict__ wsB2,
    float* __restrict__ out)
{
    __shared__ float  s_w[16][261];                   // 16.7 KB, one net's D matrix
    __shared__ __align__(16) ushort s_hb[2][16][64];  // 4 KB bf16 h, XOR-swizzled
    __shared__ float s_g[16][33];                     // 2.1 KB, f[src], pad 33
    __shared__ float s_emb[16][10];
    __shared__ float s_s1[16][4];
    __shared__ float s_v[80][33];                     // 10.6 KB, per-edge v
    __shared__ float s_lg[80];                        // per-edge logits
    __shared__ float s_cut[80];                       // per-edge cutoff
    __shared__ float s_mqn[4][32];                    // mq for block's 4 nodes

    const int t = threadIdx.x;
    const int wave = t >> 6, lane = t & 63;
    const int qd = lane >> 4, n = lane & 15;
    const int n0 = blockIdx.x * 4;                    // first node of block
    const int E0 = n0 * DEG;                          // first edge of block

    // ---- prologue A: mq for the block's 4 dst nodes (verbatim prep math) ----
    if (t < 128) {
        int nd = t >> 5, idx = t & 31;
        const float* fr = f + (size_t)(n0 + nd) * 32;
        const float inv8 = 0.35355339059327373f; // 1/sqrt(8)
        float o_ = 0.0f;
        if (idx < 8) {
            int j = idx;
            #pragma unroll
            for (int i = 0; i < 8; i++) {
                float qs = 0.0f;
                #pragma unroll
                for (int a = 0; a < 8; a++) qs = fmaf(fr[a], Wqs[a * 8 + i], qs);
                o_ = fmaf(qs * inv8, Wds[i * 8 + j], o_);
            }
        } else {
            int kk = idx - 8;
            int j = kk / 3, c = kk - 3 * j;
            #pragma unroll
            for (int i = 0; i < 8; i++) {
                float qv = 0.0f;
                #pragma unroll
                for (int a = 0; a < 8; a++) qv = fmaf(fr[8 + 3 * a + c], Wqv[a * 8 + i], qv);
                o_ = fmaf(qv * inv8, Wdv[i * 8 + j], o_);
            }
            o_ *= 0.5773502691896258f; // 1/sqrt(3)
        }
        s_mqn[nd][idx] = o_;
    }

    // ---- prologue B: k-net B fragments (one net at a time, 32 VGPR) ----
    short8 bcur[2][4]; // [kstep][jj]
    #pragma unroll
    for (int s = 0; s < 2; s++)
        #pragma unroll
        for (int jj = 0; jj < 4; jj++)
            bcur[s][jj] = *(const short8*)&wsB2[s * 1024 + (wave * 4 + jj) * 64 + lane];

    for (int g = 0; g < NGRP; g++) {
        const int le0 = g * 16;            // local edge base
        const int e0 = E0 + le0;

        // ---- phase A: geometry + radial basis (threads 0..15) ----
        if (t < 16) {
            int e = e0 + t;
            int s = esrc[e];
            int d = n0 + (le0 + t) / DEG;  // edst[e] == e/20
            float vx = pos[s * 3 + 0] - pos[d * 3 + 0];
            float vy = pos[s * 3 + 1] - pos[d * 3 + 1];
            float vz = pos[s * 3 + 2] - pos[d * 3 + 2];
            float r = sqrtf(vx * vx + vy * vy + vz * vz);
            float invr = 1.0f / r;
            const float sqrt3 = 1.7320508075688772f;
            s_s1[t][0] = sqrt3 * vx * invr;
            s_s1[t][1] = sqrt3 * vy * invr;
            s_s1[t][2] = sqrt3 * vz * invr;
            s_cut[le0 + t] = su_f(10.0f * (1.0f - r / RMAXF));
            const float step = RMAXF / 11.0f;
            const float invstep = 11.0f / RMAXF;
            const float K = 26.66929988626f; // 1.14136*e^2*sqrt(10)
            #pragma unroll
            for (int j = 0; j < 10; j++) {
                float dd = (r - step * (float)(j + 1)) * invstep;
                s_emb[t][j] = K * su_f(dd + 1.0f) * su_f(1.0f - dd);
            }
        }
        // ---- phase A2: stage gathered f[src] rows ----
        {
            int el = t >> 4, j = t & 15;
            int s = esrc[e0 + el];
            s_g[el][j]      = f[(size_t)s * 32 + j];
            s_g[el][16 + j] = f[(size_t)s * 32 + 16 + j];
        }
        __syncthreads(); // barrier 1

        // ---- phase B: scalar GEMM1 + silu (both nets) -> s_hb ----
        {
            const float invsq10 = 0.31622776601683794f; // 1/sqrt(10)
            #pragma unroll
            for (int e = 0; e < 4; e++) {
                int el = wave * 4 + e;
                float ak = 0.0f, av = 0.0f;
                #pragma unroll
                for (int j = 0; j < 10; j++) {
                    float ej = s_emb[el][j];
                    ak = fmaf(ej, Wk1[j * 64 + lane], ak);
                    av = fmaf(ej, Wv1[j * 64 + lane], av);
                }
                ak *= invsq10; av *= invsq10;
                float hk = ak / (1.0f + __expf(-ak));
                float hv = av / (1.0f + __expf(-av));
                int pos_ = ((((lane >> 3) ^ (el & 7))) << 3) | (lane & 7);
                s_hb[0][el][pos_] = f2bf(hk);
                s_hb[1][el][pos_] = f2bf(hv);
            }
        }
        __syncthreads(); // barrier 2

        // ---- phase C0: k-net MFMA -> s_w; prefetch v-net B fragments ----
        {
            short8 ha0 = *(const short8*)&s_hb[0][n][((qd ^ (n & 7)) << 3)];
            short8 ha1 = *(const short8*)&s_hb[0][n][(((4 + qd) ^ (n & 7)) << 3)];
            #pragma unroll
            for (int jj = 0; jj < 4; jj++) {
                int tt = wave * 4 + jj;
                f32x4 d = {0.0f, 0.0f, 0.0f, 0.0f};
                d = __builtin_amdgcn_mfma_f32_16x16x32_bf16(ha0, bcur[0][jj], d, 0, 0, 0);
                d = __builtin_amdgcn_mfma_f32_16x16x32_bf16(ha1, bcur[1][jj], d, 0, 0, 0);
                #pragma unroll
                for (int r = 0; r < 4; r++)
                    s_w[4 * qd + r][tt * 16 + n] = d[r]; // D: row=4*quad+reg, col=n
            }
            #pragma unroll
            for (int s = 0; s < 2; s++)
                #pragma unroll
                for (int jj = 0; jj < 4; jj++)
                    bcur[s][jj] = *(const short8*)&wsB2[2048 + s * 1024 +
                                                        (wave * 4 + jj) * 64 + lane];
        }
        __syncthreads(); // barrier 3

        // ---- phase D0: k-net TP + mq-logits -> s_lg (round-6 math) ----
        {
            int el = t >> 4, role = t & 15;
            int nd = (le0 + el) / DEG;     // local dst node of this edge
            float s1x = s_s1[el][0], s1y = s_s1[el][1], s1z = s_s1[el][2];
            const float inv_sqrt3 = 0.5773502691896258f;
            float a[8], b[8];
            #pragma unroll
            for (int i = 0; i < 8; i++) {
                a[i] = s_g[el][i];
                b[i] = (s_g[el][8 + i * 3 + 0] * s1x +
                        s_g[el][8 + i * 3 + 1] * s1y +
                        s_g[el][8 + i * 3 + 2] * s1z) * inv_sqrt3;
            }
            const float nrm = 0.25f; // 1/(sqrt(8)*sqrt(2))
            const float* wk = s_w[el];
            float contrib = 0.0f;
            if (role < 8) {
                int o = role;
                float ks = 0.0f;
                #pragma unroll
                for (int i = 0; i < 8; i++)
                    ks += a[i] * wk[i * 8 + o] + b[i] * wk[64 + i * 8 + o];
                contrib = s_mqn[nd][o] * (ks * nrm);
            } else {
                int o = role - 8;
                #pragma unroll
                for (int c = 0; c < 3; c++) {
                    float uk = 0.0f, tk = 0.0f;
                    #pragma unroll
                    for (int i = 0; i < 8; i++) {
                        uk += a[i] * wk[128 + i * 8 + o];
                        tk = fmaf(s_g[el][8 + i * 3 + c], wk[192 + i * 8 + o], tk);
                    }
                    float kv_c = nrm * (s_s1[el][c] * uk + tk);
                    contrib = fmaf(s_mqn[nd][8 + 3 * o + c], kv_c, contrib);
                }
            }
            contrib += __shfl_xor(contrib, 1);
            contrib += __shfl_xor(contrib, 2);
            contrib += __shfl_xor(contrib, 4);
            contrib += __shfl_xor(contrib, 8);
            if (role == 0) s_lg[le0 + el] = contrib * 0.08838834764831845f; // 1/(8*sqrt2)
        }
        __syncthreads(); // barrier 4

        // ---- phase C1: v-net MFMA -> s_w; prefetch k-net (next group) ----
        {
            short8 ha0 = *(const short8*)&s_hb[1][n][((qd ^ (n & 7)) << 3)];
            short8 ha1 = *(const short8*)&s_hb[1][n][(((4 + qd) ^ (n & 7)) << 3)];
            #pragma unroll
            for (int jj = 0; jj < 4; jj++) {
                int tt = wave * 4 + jj;
                f32x4 d = {0.0f, 0.0f, 0.0f, 0.0f};
                d = __builtin_amdgcn_mfma_f32_16x16x32_bf16(ha0, bcur[0][jj], d, 0, 0, 0);
                d = __builtin_amdgcn_mfma_f32_16x16x32_bf16(ha1, bcur[1][jj], d, 0, 0, 0);
                #pragma unroll
                for (int r = 0; r < 4; r++)
                    s_w[4 * qd + r][tt * 16 + n] = d[r];
            }
            #pragma unroll
            for (int s = 0; s < 2; s++)
                #pragma unroll
                for (int jj = 0; jj < 4; jj++)
                    bcur[s][jj] = *(const short8*)&wsB2[s * 1024 +
                                                        (wave * 4 + jj) * 64 + lane];
        }
        __syncthreads(); // barrier 5

        // ---- phase D1: v-net TP -> s_v (round-6 math) ----
        {
            int el = t >> 4, role = t & 15;
            int le = le0 + el;
            float s1x = s_s1[el][0], s1y = s_s1[el][1], s1z = s_s1[el][2];
            const float inv_sqrt3 = 0.5773502691896258f;
            float a[8], b[8];
            #pragma unroll
            for (int i = 0; i < 8; i++) {
                a[i] = s_g[el][i];
                b[i] = (s_g[el][8 + i * 3 + 0] * s1x +
                        s_g[el][8 + i * 3 + 1] * s1y +
                        s_g[el][8 + i * 3 + 2] * s1z) * inv_sqrt3;
            }
            const float nrm = 0.25f;
            const float* wv = s_w[el];
            if (role < 8) {
                int o = role;
                float vs = 0.0f;
                #pragma unroll
                for (int i = 0; i < 8; i++)
                    vs += a[i] * wv[i * 8 + o] + b[i] * wv[64 + i * 8 + o];
                s_v[le][o] = vs * nrm;
            } else {
                int o = role - 8;
                #pragma unroll
                for (int c = 0; c < 3; c++) {
                    float uv = 0.0f, tv = 0.0f;
                    #pragma unroll
                    for (int i = 0; i < 8; i++) {
                        uv += a[i] * wv[128 + i * 8 + o];
                        tv = fmaf(s_g[el][8 + i * 3 + c], wv[192 + i * 8 + o], tv);
                    }
                    s_v[le][8 + o * 3 + c] = nrm * (s_s1[el][c] * uv + tv);
                }
            }
        }
        __syncthreads(); // barrier 6: protects s_* for next group / epilogue
    }

    // ---- epilogue: per-node softmax + weighted sum (proven out_kernel math).
    //      wave w handles node n0+w; both 32-lane halves compute identically.
    {
        int base_le = DEG * wave;
        int h32 = lane & 32;
        int hl = lane & 31;
        float lg = -INFINITY, cw = 0.0f;
        if (hl < DEG) {
            lg = s_lg[base_le + hl];
            cw = s_cut[base_le + hl];
        }
        float mx = lg;
        mx = fmaxf(mx, __shfl_xor(mx, 16));
        mx = fmaxf(mx, __shfl_xor(mx, 8));
        mx = fmaxf(mx, __shfl_xor(mx, 4));
        mx = fmaxf(mx, __shfl_xor(mx, 2));
        mx = fmaxf(mx, __shfl_xor(mx, 1));

        float ew = cw * __expf(lg - mx);
        float z = ew;
        z += __shfl_xor(z, 16);
        z += __shfl_xor(z, 8);
        z += __shfl_xor(z, 4);
        z += __shfl_xor(z, 2);
        z += __shfl_xor(z, 1);
        z = (z == 0.0f) ? 1.0f : z;
        float coef = sqrtf(ew / z + 1e-12f);

        float acc = 0.0f;
        #pragma unroll
        for (int ee = 0; ee < DEG; ee++) {
            float ce = __shfl(coef, h32 + ee);
            acc = fmaf(ce, s_v[base_le + ee][hl], acc);
        }
        if (lane < 32) out[(size_t)(n0 + wave) * 32 + hl] = acc;
    }
}

// ---------------------------------------------------------------------------
extern "C" void kernel_launch(void* const* d_in, const int* in_sizes, int n_in,
                              void* d_out, int out_size, void* d_ws, size_t ws_size,
                              hipStream_t stream) {
    const float* f    = (const float*)d_in[0];
    const float* pos  = (const float*)d_in[1];
    const float* Wqs  = (const float*)d_in[2];
    const float* Wqv  = (const float*)d_in[3];
    const float* Wk1  = (const float*)d_in[4];
    const float* Wk2  = (const float*)d_in[5];
    const float* Wv1  = (const float*)d_in[6];
    const float* Wv2  = (const float*)d_in[7];
    const float* Wds  = (const float*)d_in[8];
    const float* Wdv  = (const float*)d_in[9];
    const int* esrc   = (const int*)d_in[10];
    float* out        = (float*)d_out;

    uint4* wsB2 = (uint4*)d_ws;   // 65536 B

    pack_kernel<<<dim3(16), dim3(256), 0, stream>>>(Wk2, Wv2, wsB2);
    edge_kernel<<<dim3(NN / 4), dim3(256), 0, stream>>>(
        f, pos, Wqs, Wqv, Wds, Wdv, Wk1, Wv1, esrc, wsB2, out);
}

// Round 11
// 245.347 us; speedup vs baseline: 1.2792x; 1.0333x over previous
//
#include <hip/hip_runtime.h>
#include <hip/hip_bf16.h>
#include <math.h>

#define NN 16384
#define DEG 20
#define EE (NN*DEG)
#define RMAXF 3.5f
#define NGRP 5   // groups of 16 edges per block (80 edges = 4 nodes)

typedef __attribute__((ext_vector_type(8))) short short8;
typedef __attribute__((ext_vector_type(4))) float f32x4;

// soft_unit_step: exp(-1/x) for x>0 else 0
__device__ __forceinline__ float su_f(float x) {
    return x > 0.0f ? __expf(-1.0f / x) : 0.0f;
}
__device__ __forceinline__ ushort f2bf(float x) {
    __hip_bfloat16 h = __float2bfloat16(x);
    return *reinterpret_cast<ushort*>(&h);
}

// ---------------------------------------------------------------------------
// pack_kernel: W2 -> bf16 MFMA B-fragments (proven). Scale 1/8.
// B-frag lane(q=lane>>4, n=lane&15): 8 bf16 = W2[k=s*32+q*8+j][col=tt*16+n]
// wsB2 layout: [net][kstep s][tile tt (16)][lane (64)] as uint4.
// ---------------------------------------------------------------------------
__global__ __launch_bounds__(256) void pack_kernel(
    const float* __restrict__ Wk2, const float* __restrict__ Wv2,
    uint4* __restrict__ wsB2)
{
    int tid = blockIdx.x * 256 + threadIdx.x;
    int net = tid >> 11, s = (tid >> 10) & 1, tt = (tid >> 6) & 15, lane = tid & 63;
    int qq = lane >> 4, n = lane & 15, col = tt * 16 + n;
    const float* W2 = net ? Wv2 : Wk2;
    unsigned int r[4];
    #pragma unroll
    for (int jj = 0; jj < 4; jj++) {
        int k0 = s * 32 + qq * 8 + 2 * jj;
        unsigned int lo = f2bf(W2[k0 * 256 + col] * 0.125f);
        unsigned int hi = f2bf(W2[(k0 + 1) * 256 + col] * 0.125f);
        r[jj] = lo | (hi << 16);
    }
    wsB2[tid] = make_uint4(r[0], r[1], r[2], r[3]);
}

// ---------------------------------------------------------------------------
// edge_kernel: block = 256 threads = 4 waves; owns 4 whole nodes (80 edges,
// 5 groups of 16). Round-10 fusion + round-6 dual-net phases:
//  - dual s_w[2] (both nets' D resident), dual breg loaded once in prologue
//  - 4 barriers/group (was 6); phase D computes a/b once for both nets
// Relies on edst[e] == e/20 (contiguous segments; exploited since round 1).
// ---------------------------------------------------------------------------
__global__ __launch_bounds__(256, 3) void edge_kernel(
    const float* __restrict__ f,   const float* __restrict__ pos,
    const float* __restrict__ Wqs, const float* __restrict__ Wqv,
    const float* __restrict__ Wds, const float* __restrict__ Wdv,
    const float* __restrict__ Wk1, const float* __restrict__ Wv1,
    const int* __restrict__ esrc,  const uint4* __restrict__ wsB2,
    float* __restrict__ out)
{
    __shared__ float  s_w[2][16][261];                // 33.4 KB, D matrices (k,v)
    __shared__ __align__(16) ushort s_hb[2][16][64];  // 4 KB bf16 h, XOR-swizzled
    __shared__ float s_g[16][33];                     // 2.1 KB, f[src], pad 33
    __shared__ float s_emb[16][10];
    __shared__ float s_s1[16][4];
    __shared__ float s_v[80][33];                     // 10.6 KB, per-edge v
    __shared__ float s_lg[80];                        // per-edge logits
    __shared__ float s_cut[80];                       // per-edge cutoff
    __shared__ float s_mqn[4][32];                    // mq for block's 4 nodes

    const int t = threadIdx.x;
    const int wave = t >> 6, lane = t & 63;
    const int qd = lane >> 4, n = lane & 15;
    const int n0 = blockIdx.x * 4;                    // first node of block
    const int E0 = n0 * DEG;                          // first edge of block

    // ---- prologue A: mq for the block's 4 dst nodes (verbatim prep math) ----
    if (t < 128) {
        int nd = t >> 5, idx = t & 31;
        const float* fr = f + (size_t)(n0 + nd) * 32;
        const float inv8 = 0.35355339059327373f; // 1/sqrt(8)
        float o_ = 0.0f;
        if (idx < 8) {
            int j = idx;
            #pragma unroll
            for (int i = 0; i < 8; i++) {
                float qs = 0.0f;
                #pragma unroll
                for (int a = 0; a < 8; a++) qs = fmaf(fr[a], Wqs[a * 8 + i], qs);
                o_ = fmaf(qs * inv8, Wds[i * 8 + j], o_);
            }
        } else {
            int kk = idx - 8;
            int j = kk / 3, c = kk - 3 * j;
            #pragma unroll
            for (int i = 0; i < 8; i++) {
                float qv = 0.0f;
                #pragma unroll
                for (int a = 0; a < 8; a++) qv = fmaf(fr[8 + 3 * a + c], Wqv[a * 8 + i], qv);
                o_ = fmaf(qv * inv8, Wdv[i * 8 + j], o_);
            }
            o_ *= 0.5773502691896258f; // 1/sqrt(3)
        }
        s_mqn[nd][idx] = o_;
    }

    // ---- prologue B: B fragments for this wave's 4 tiles, both nets ----
    short8 breg[2][2][4]; // [net][kstep][jj]
    #pragma unroll
    for (int net = 0; net < 2; net++)
        #pragma unroll
        for (int s = 0; s < 2; s++)
            #pragma unroll
            for (int jj = 0; jj < 4; jj++)
                breg[net][s][jj] = *(const short8*)&wsB2[net * 2048 + s * 1024 +
                                                         (wave * 4 + jj) * 64 + lane];

    for (int g = 0; g < NGRP; g++) {
        const int le0 = g * 16;            // local edge base
        const int e0 = E0 + le0;

        // ---- phase A: geometry + radial basis (threads 0..15) ----
        if (t < 16) {
            int e = e0 + t;
            int s = esrc[e];
            int d = n0 + (le0 + t) / DEG;  // edst[e] == e/20
            float vx = pos[s * 3 + 0] - pos[d * 3 + 0];
            float vy = pos[s * 3 + 1] - pos[d * 3 + 1];
            float vz = pos[s * 3 + 2] - pos[d * 3 + 2];
            float r = sqrtf(vx * vx + vy * vy + vz * vz);
            float invr = 1.0f / r;
            const float sqrt3 = 1.7320508075688772f;
            s_s1[t][0] = sqrt3 * vx * invr;
            s_s1[t][1] = sqrt3 * vy * invr;
            s_s1[t][2] = sqrt3 * vz * invr;
            s_cut[le0 + t] = su_f(10.0f * (1.0f - r / RMAXF));
            const float step = RMAXF / 11.0f;
            const float invstep = 11.0f / RMAXF;
            const float K = 26.66929988626f; // 1.14136*e^2*sqrt(10)
            #pragma unroll
            for (int j = 0; j < 10; j++) {
                float dd = (r - step * (float)(j + 1)) * invstep;
                s_emb[t][j] = K * su_f(dd + 1.0f) * su_f(1.0f - dd);
            }
        }
        // ---- phase A2: stage gathered f[src] rows ----
        {
            int el = t >> 4, j = t & 15;
            int s = esrc[e0 + el];
            s_g[el][j]      = f[(size_t)s * 32 + j];
            s_g[el][16 + j] = f[(size_t)s * 32 + 16 + j];
        }
        __syncthreads(); // barrier 1

        // ---- phase B: scalar GEMM1 + silu (both nets) -> s_hb ----
        {
            const float invsq10 = 0.31622776601683794f; // 1/sqrt(10)
            #pragma unroll
            for (int e = 0; e < 4; e++) {
                int el = wave * 4 + e;
                float ak = 0.0f, av = 0.0f;
                #pragma unroll
                for (int j = 0; j < 10; j++) {
                    float ej = s_emb[el][j];
                    ak = fmaf(ej, Wk1[j * 64 + lane], ak);
                    av = fmaf(ej, Wv1[j * 64 + lane], av);
                }
                ak *= invsq10; av *= invsq10;
                float hk = ak / (1.0f + __expf(-ak));
                float hv = av / (1.0f + __expf(-av));
                int pos_ = ((((lane >> 3) ^ (el & 7))) << 3) | (lane & 7);
                s_hb[0][el][pos_] = f2bf(hk);
                s_hb[1][el][pos_] = f2bf(hv);
            }
        }
        __syncthreads(); // barrier 2

        // ---- phase C: MFMA GEMM2 for both nets -> s_w[net] ----
        #pragma unroll
        for (int net = 0; net < 2; net++) {
            short8 ha0 = *(const short8*)&s_hb[net][n][((qd ^ (n & 7)) << 3)];
            short8 ha1 = *(const short8*)&s_hb[net][n][(((4 + qd) ^ (n & 7)) << 3)];
            #pragma unroll
            for (int jj = 0; jj < 4; jj++) {
                int tt = wave * 4 + jj;
                f32x4 d = {0.0f, 0.0f, 0.0f, 0.0f};
                d = __builtin_amdgcn_mfma_f32_16x16x32_bf16(ha0, breg[net][0][jj], d, 0, 0, 0);
                d = __builtin_amdgcn_mfma_f32_16x16x32_bf16(ha1, breg[net][1][jj], d, 0, 0, 0);
                #pragma unroll
                for (int r = 0; r < 4; r++)
                    s_w[net][4 * qd + r][tt * 16 + n] = d[r]; // D: row=4*quad+reg, col=n
            }
        }
        __syncthreads(); // barrier 3

        // ---- phase D: a/b once; k-net TP + mq-logits -> s_lg; v-net TP -> s_v ----
        {
            int el = t >> 4, role = t & 15;
            int le = le0 + el;
            int nd = le / DEG;             // local dst node of this edge
            float s1x = s_s1[el][0], s1y = s_s1[el][1], s1z = s_s1[el][2];
            const float inv_sqrt3 = 0.5773502691896258f;
            float a[8], b[8];
            #pragma unroll
            for (int i = 0; i < 8; i++) {
                a[i] = s_g[el][i];
                b[i] = (s_g[el][8 + i * 3 + 0] * s1x +
                        s_g[el][8 + i * 3 + 1] * s1y +
                        s_g[el][8 + i * 3 + 2] * s1z) * inv_sqrt3;
            }
            const float nrm = 0.25f; // 1/(sqrt(8)*sqrt(2))

            // --- k-net: this role's ks/kv contracted with mq ---
            const float* wk = s_w[0][el];
            float contrib = 0.0f;
            if (role < 8) {
                int o = role;
                float ks = 0.0f;
                #pragma unroll
                for (int i = 0; i < 8; i++)
                    ks += a[i] * wk[i * 8 + o] + b[i] * wk[64 + i * 8 + o];
                contrib = s_mqn[nd][o] * (ks * nrm);
            } else {
                int o = role - 8;
                #pragma unroll
                for (int c = 0; c < 3; c++) {
                    float uk = 0.0f, tk = 0.0f;
                    #pragma unroll
                    for (int i = 0; i < 8; i++) {
                        uk += a[i] * wk[128 + i * 8 + o];
                        tk = fmaf(s_g[el][8 + i * 3 + c], wk[192 + i * 8 + o], tk);
                    }
                    float kv_c = nrm * (s_s1[el][c] * uk + tk);
                    contrib = fmaf(s_mqn[nd][8 + 3 * o + c], kv_c, contrib);
                }
            }
            contrib += __shfl_xor(contrib, 1);
            contrib += __shfl_xor(contrib, 2);
            contrib += __shfl_xor(contrib, 4);
            contrib += __shfl_xor(contrib, 8);
            if (role == 0) s_lg[le] = contrib * 0.08838834764831845f; // 1/(8*sqrt2)

            // --- v-net TP -> s_v ---
            const float* wv = s_w[1][el];
            if (role < 8) {
                int o = role;
                float vs = 0.0f;
                #pragma unroll
                for (int i = 0; i < 8; i++)
                    vs += a[i] * wv[i * 8 + o] + b[i] * wv[64 + i * 8 + o];
                s_v[le][o] = vs * nrm;
            } else {
                int o = role - 8;
                #pragma unroll
                for (int c = 0; c < 3; c++) {
                    float uv = 0.0f, tv = 0.0f;
                    #pragma unroll
                    for (int i = 0; i < 8; i++) {
                        uv += a[i] * wv[128 + i * 8 + o];
                        tv = fmaf(s_g[el][8 + i * 3 + c], wv[192 + i * 8 + o], tv);
                    }
                    s_v[le][8 + o * 3 + c] = nrm * (s_s1[el][c] * uv + tv);
                }
            }
        }
        __syncthreads(); // barrier 4: protects s_* for next group / epilogue
    }

    // ---- epilogue: per-node softmax + weighted sum (proven out_kernel math).
    //      wave w handles node n0+w; both 32-lane halves compute identically.
    {
        int base_le = DEG * wave;
        int h32 = lane & 32;
        int hl = lane & 31;
        float lg = -INFINITY, cw = 0.0f;
        if (hl < DEG) {
            lg = s_lg[base_le + hl];
            cw = s_cut[base_le + hl];
        }
        float mx = lg;
        mx = fmaxf(mx, __shfl_xor(mx, 16));
        mx = fmaxf(mx, __shfl_xor(mx, 8));
        mx = fmaxf(mx, __shfl_xor(mx, 4));
        mx = fmaxf(mx, __shfl_xor(mx, 2));
        mx = fmaxf(mx, __shfl_xor(mx, 1));

        float ew = cw * __expf(lg - mx);
        float z = ew;
        z += __shfl_xor(z, 16);
        z += __shfl_xor(z, 8);
        z += __shfl_xor(z, 4);
        z += __shfl_xor(z, 2);
        z += __shfl_xor(z, 1);
        z = (z == 0.0f) ? 1.0f : z;
        float coef = sqrtf(ew / z + 1e-12f);

        float acc = 0.0f;
        #pragma unroll
        for (int ee = 0; ee < DEG; ee++) {
            float ce = __shfl(coef, h32 + ee);
            acc = fmaf(ce, s_v[base_le + ee][hl], acc);
        }
        if (lane < 32) out[(size_t)(n0 + wave) * 32 + hl] = acc;
    }
}

// ---------------------------------------------------------------------------
extern "C" void kernel_launch(void* const* d_in, const int* in_sizes, int n_in,
                              void* d_out, int out_size, void* d_ws, size_t ws_size,
                              hipStream_t stream) {
    const float* f    = (const float*)d_in[0];
    const float* pos  = (const float*)d_in[1];
    const float* Wqs  = (const float*)d_in[2];
    const float* Wqv  = (const float*)d_in[3];
    const float* Wk1  = (const float*)d_in[4];
    const float* Wk2  = (const float*)d_in[5];
    const float* Wv1  = (const float*)d_in[6];
    const float* Wv2  = (const float*)d_in[7];
    const float* Wds  = (const float*)d_in[8];
    const float* Wdv  = (const float*)d_in[9];
    const int* esrc   = (const int*)d_in[10];
    float* out        = (float*)d_out;

    uint4* wsB2 = (uint4*)d_ws;   // 65536 B

    pack_kernel<<<dim3(16), dim3(256), 0, stream>>>(Wk2, Wv2, wsB2);
    edge_kernel<<<dim3(NN / 4), dim3(256), 0, stream>>>(
        f, pos, Wqs, Wqv, Wds, Wdv, Wk1, Wv1, esrc, wsB2, out);
}

// Round 12
// 244.261 us; speedup vs baseline: 1.2848x; 1.0044x over previous
//
#include <hip/hip_runtime.h>
#include <hip/hip_bf16.h>
#include <math.h>

#define NN 16384
#define DEG 20
#define EE (NN*DEG)
#define RMAXF 3.5f
#define NGRP 5   // groups of 16 edges per block (80 edges = 4 nodes)

typedef __attribute__((ext_vector_type(8))) short short8;
typedef __attribute__((ext_vector_type(4))) float f32x4;

// soft_unit_step: exp(-1/x) for x>0 else 0
__device__ __forceinline__ float su_f(float x) {
    return x > 0.0f ? __expf(-1.0f / x) : 0.0f;
}
__device__ __forceinline__ ushort f2bf(float x) {
    __hip_bfloat16 h = __float2bfloat16(x);
    return *reinterpret_cast<ushort*>(&h);
}

// ---------------------------------------------------------------------------
// edge_kernel (single launch): block = 256 threads = 4 waves; owns 4 whole
// nodes (80 edges, 5 groups of 16). Round-11 structure with:
//  - B fragments packed per-thread directly from W2 in the prologue
//    (identical f2bf(x*0.125f) math as the old pack_kernel; no ws round-trip)
//  - W1 hoisted into 20 registers (was 20 global loads/thread/group)
//  - s_g padded to 36 (16B-aligned rows) and phase D reads it as 8x float4
// Relies on edst[e] == e/20 (contiguous segments; exploited since round 1).
// ---------------------------------------------------------------------------
__global__ __launch_bounds__(256, 3) void edge_kernel(
    const float* __restrict__ f,   const float* __restrict__ pos,
    const float* __restrict__ Wqs, const float* __restrict__ Wqv,
    const float* __restrict__ Wds, const float* __restrict__ Wdv,
    const float* __restrict__ Wk1, const float* __restrict__ Wv1,
    const float* __restrict__ Wk2, const float* __restrict__ Wv2,
    const int* __restrict__ esrc,  float* __restrict__ out)
{
    __shared__ float  s_w[2][16][261];                // 33.4 KB, D matrices (k,v)
    __shared__ __align__(16) ushort s_hb[2][16][64];  // 4 KB bf16 h, XOR-swizzled
    __shared__ __align__(16) float s_g[16][36];       // 2.25 KB, f[src], pad 36
    __shared__ float s_emb[16][10];
    __shared__ float s_s1[16][4];
    __shared__ float s_v[80][33];                     // 10.6 KB, per-edge v
    __shared__ float s_lg[80];                        // per-edge logits
    __shared__ float s_cut[80];                       // per-edge cutoff
    __shared__ float s_mqn[4][32];                    // mq for block's 4 nodes

    const int t = threadIdx.x;
    const int wave = t >> 6, lane = t & 63;
    const int qd = lane >> 4, n = lane & 15;
    const int n0 = blockIdx.x * 4;                    // first node of block
    const int E0 = n0 * DEG;                          // first edge of block

    // ---- prologue A: mq for the block's 4 dst nodes (verbatim prep math) ----
    if (t < 128) {
        int nd = t >> 5, idx = t & 31;
        const float* fr = f + (size_t)(n0 + nd) * 32;
        const float inv8 = 0.35355339059327373f; // 1/sqrt(8)
        float o_ = 0.0f;
        if (idx < 8) {
            int j = idx;
            #pragma unroll
            for (int i = 0; i < 8; i++) {
                float qs = 0.0f;
                #pragma unroll
                for (int a = 0; a < 8; a++) qs = fmaf(fr[a], Wqs[a * 8 + i], qs);
                o_ = fmaf(qs * inv8, Wds[i * 8 + j], o_);
            }
        } else {
            int kk = idx - 8;
            int j = kk / 3, c = kk - 3 * j;
            #pragma unroll
            for (int i = 0; i < 8; i++) {
                float qv = 0.0f;
                #pragma unroll
                for (int a = 0; a < 8; a++) qv = fmaf(fr[8 + 3 * a + c], Wqv[a * 8 + i], qv);
                o_ = fmaf(qv * inv8, Wdv[i * 8 + j], o_);
            }
            o_ *= 0.5773502691896258f; // 1/sqrt(3)
        }
        s_mqn[nd][idx] = o_;
    }

    // ---- prologue B: W1 rows for this lane (20 regs) ----
    float wk1r[10], wv1r[10];
    #pragma unroll
    for (int j = 0; j < 10; j++) {
        wk1r[j] = Wk1[j * 64 + lane];
        wv1r[j] = Wv1[j * 64 + lane];
    }

    // ---- prologue C: B fragments packed directly from W2 (both nets) ----
    // breg[net][s][jj] = 8 bf16: W2[k=s*32+qd*8+j][col=(wave*4+jj)*16+n]*0.125
    short8 breg[2][2][4];
    #pragma unroll
    for (int net = 0; net < 2; net++) {
        const float* W2 = net ? Wv2 : Wk2;
        #pragma unroll
        for (int s = 0; s < 2; s++)
            #pragma unroll
            for (int jj = 0; jj < 4; jj++) {
                int col = (wave * 4 + jj) * 16 + n;
                union { ushort u[8]; short8 v; } bf;
                #pragma unroll
                for (int j = 0; j < 8; j++) {
                    int k0 = s * 32 + qd * 8 + j;
                    bf.u[j] = f2bf(W2[k0 * 256 + col] * 0.125f);
                }
                breg[net][s][jj] = bf.v;
            }
    }

    for (int g = 0; g < NGRP; g++) {
        const int le0 = g * 16;            // local edge base
        const int e0 = E0 + le0;

        // ---- phase A: geometry + radial basis (threads 0..15) ----
        if (t < 16) {
            int e = e0 + t;
            int s = esrc[e];
            int d = n0 + (le0 + t) / DEG;  // edst[e] == e/20
            float vx = pos[s * 3 + 0] - pos[d * 3 + 0];
            float vy = pos[s * 3 + 1] - pos[d * 3 + 1];
            float vz = pos[s * 3 + 2] - pos[d * 3 + 2];
            float r = sqrtf(vx * vx + vy * vy + vz * vz);
            float invr = 1.0f / r;
            const float sqrt3 = 1.7320508075688772f;
            s_s1[t][0] = sqrt3 * vx * invr;
            s_s1[t][1] = sqrt3 * vy * invr;
            s_s1[t][2] = sqrt3 * vz * invr;
            s_cut[le0 + t] = su_f(10.0f * (1.0f - r / RMAXF));
            const float step = RMAXF / 11.0f;
            const float invstep = 11.0f / RMAXF;
            const float K = 26.66929988626f; // 1.14136*e^2*sqrt(10)
            #pragma unroll
            for (int j = 0; j < 10; j++) {
                float dd = (r - step * (float)(j + 1)) * invstep;
                s_emb[t][j] = K * su_f(dd + 1.0f) * su_f(1.0f - dd);
            }
        }
        // ---- phase A2: stage gathered f[src] rows (float4, threads 0..127) ----
        if (t < 128) {
            int el = t >> 3, c4 = t & 7;
            int s = esrc[e0 + el];
            float4 x = *reinterpret_cast<const float4*>(f + (size_t)s * 32 + c4 * 4);
            *reinterpret_cast<float4*>(&s_g[el][c4 * 4]) = x;
        }
        __syncthreads(); // barrier 1

        // ---- phase B: GEMM1 (W1 in regs) + silu (both nets) -> s_hb ----
        {
            const float invsq10 = 0.31622776601683794f; // 1/sqrt(10)
            #pragma unroll
            for (int e = 0; e < 4; e++) {
                int el = wave * 4 + e;
                float ak = 0.0f, av = 0.0f;
                #pragma unroll
                for (int j = 0; j < 10; j++) {
                    float ej = s_emb[el][j];
                    ak = fmaf(ej, wk1r[j], ak);
                    av = fmaf(ej, wv1r[j], av);
                }
                ak *= invsq10; av *= invsq10;
                float hk = ak / (1.0f + __expf(-ak));
                float hv = av / (1.0f + __expf(-av));
                int pos_ = ((((lane >> 3) ^ (el & 7))) << 3) | (lane & 7);
                s_hb[0][el][pos_] = f2bf(hk);
                s_hb[1][el][pos_] = f2bf(hv);
            }
        }
        __syncthreads(); // barrier 2

        // ---- phase C: MFMA GEMM2 for both nets -> s_w[net] ----
        #pragma unroll
        for (int net = 0; net < 2; net++) {
            short8 ha0 = *(const short8*)&s_hb[net][n][((qd ^ (n & 7)) << 3)];
            short8 ha1 = *(const short8*)&s_hb[net][n][(((4 + qd) ^ (n & 7)) << 3)];
            #pragma unroll
            for (int jj = 0; jj < 4; jj++) {
                int tt = wave * 4 + jj;
                f32x4 d = {0.0f, 0.0f, 0.0f, 0.0f};
                d = __builtin_amdgcn_mfma_f32_16x16x32_bf16(ha0, breg[net][0][jj], d, 0, 0, 0);
                d = __builtin_amdgcn_mfma_f32_16x16x32_bf16(ha1, breg[net][1][jj], d, 0, 0, 0);
                #pragma unroll
                for (int r = 0; r < 4; r++)
                    s_w[net][4 * qd + r][tt * 16 + n] = d[r]; // D: row=4*quad+reg, col=n
            }
        }
        __syncthreads(); // barrier 3

        // ---- phase D: s_g via float4; k-net TP + mq-logits; v-net TP ----
        {
            int el = t >> 4, role = t & 15;
            int le = le0 + el;
            int nd = le / DEG;             // local dst node of this edge
            float s1x = s_s1[el][0], s1y = s_s1[el][1], s1z = s_s1[el][2];
            const float inv_sqrt3 = 0.5773502691896258f;
            float g[32];
            #pragma unroll
            for (int v4 = 0; v4 < 8; v4++) {
                float4 x = *reinterpret_cast<const float4*>(&s_g[el][v4 * 4]);
                g[v4 * 4 + 0] = x.x; g[v4 * 4 + 1] = x.y;
                g[v4 * 4 + 2] = x.z; g[v4 * 4 + 3] = x.w;
            }
            float a[8], b[8];
            #pragma unroll
            for (int i = 0; i < 8; i++) {
                a[i] = g[i];
                b[i] = (g[8 + i * 3 + 0] * s1x +
                        g[8 + i * 3 + 1] * s1y +
                        g[8 + i * 3 + 2] * s1z) * inv_sqrt3;
            }
            const float nrm = 0.25f; // 1/(sqrt(8)*sqrt(2))

            // --- k-net: this role's ks/kv contracted with mq ---
            const float* wk = s_w[0][el];
            float contrib = 0.0f;
            if (role < 8) {
                int o = role;
                float ks = 0.0f;
                #pragma unroll
                for (int i = 0; i < 8; i++)
                    ks += a[i] * wk[i * 8 + o] + b[i] * wk[64 + i * 8 + o];
                contrib = s_mqn[nd][o] * (ks * nrm);
            } else {
                int o = role - 8;
                #pragma unroll
                for (int c = 0; c < 3; c++) {
                    float uk = 0.0f, tk = 0.0f;
                    #pragma unroll
                    for (int i = 0; i < 8; i++) {
                        uk += a[i] * wk[128 + i * 8 + o];
                        tk = fmaf(g[8 + i * 3 + c], wk[192 + i * 8 + o], tk);
                    }
                    float kv_c = nrm * (s_s1[el][c] * uk + tk);
                    contrib = fmaf(s_mqn[nd][8 + 3 * o + c], kv_c, contrib);
                }
            }
            contrib += __shfl_xor(contrib, 1);
            contrib += __shfl_xor(contrib, 2);
            contrib += __shfl_xor(contrib, 4);
            contrib += __shfl_xor(contrib, 8);
            if (role == 0) s_lg[le] = contrib * 0.08838834764831845f; // 1/(8*sqrt2)

            // --- v-net TP -> s_v ---
            const float* wv = s_w[1][el];
            if (role < 8) {
                int o = role;
                float vs = 0.0f;
                #pragma unroll
                for (int i = 0; i < 8; i++)
                    vs += a[i] * wv[i * 8 + o] + b[i] * wv[64 + i * 8 + o];
                s_v[le][o] = vs * nrm;
            } else {
                int o = role - 8;
                #pragma unroll
                for (int c = 0; c < 3; c++) {
                    float uv = 0.0f, tv = 0.0f;
                    #pragma unroll
                    for (int i = 0; i < 8; i++) {
                        uv += a[i] * wv[128 + i * 8 + o];
                        tv = fmaf(g[8 + i * 3 + c], wv[192 + i * 8 + o], tv);
                    }
                    s_v[le][8 + o * 3 + c] = nrm * (s_s1[el][c] * uv + tv);
                }
            }
        }
        __syncthreads(); // barrier 4: protects s_* for next group / epilogue
    }

    // ---- epilogue: per-node softmax + weighted sum (proven out_kernel math).
    //      wave w handles node n0+w; both 32-lane halves compute identically.
    {
        int base_le = DEG * wave;
        int h32 = lane & 32;
        int hl = lane & 31;
        float lg = -INFINITY, cw = 0.0f;
        if (hl < DEG) {
            lg = s_lg[base_le + hl];
            cw = s_cut[base_le + hl];
        }
        float mx = lg;
        mx = fmaxf(mx, __shfl_xor(mx, 16));
        mx = fmaxf(mx, __shfl_xor(mx, 8));
        mx = fmaxf(mx, __shfl_xor(mx, 4));
        mx = fmaxf(mx, __shfl_xor(mx, 2));
        mx = fmaxf(mx, __shfl_xor(mx, 1));

        float ew = cw * __expf(lg - mx);
        float z = ew;
        z += __shfl_xor(z, 16);
        z += __shfl_xor(z, 8);
        z += __shfl_xor(z, 4);
        z += __shfl_xor(z, 2);
        z += __shfl_xor(z, 1);
        z = (z == 0.0f) ? 1.0f : z;
        float coef = sqrtf(ew / z + 1e-12f);

        float acc = 0.0f;
        #pragma unroll
        for (int ee = 0; ee < DEG; ee++) {
            float ce = __shfl(coef, h32 + ee);
            acc = fmaf(ce, s_v[base_le + ee][hl], acc);
        }
        if (lane < 32) out[(size_t)(n0 + wave) * 32 + hl] = acc;
    }
}

// ---------------------------------------------------------------------------
extern "C" void kernel_launch(void* const* d_in, const int* in_sizes, int n_in,
                              void* d_out, int out_size, void* d_ws, size_t ws_size,
                              hipStream_t stream) {
    const float* f    = (const float*)d_in[0];
    const float* pos  = (const float*)d_in[1];
    const float* Wqs  = (const float*)d_in[2];
    const float* Wqv  = (const float*)d_in[3];
    const float* Wk1  = (const float*)d_in[4];
    const float* Wk2  = (const float*)d_in[5];
    const float* Wv1  = (const float*)d_in[6];
    const float* Wv2  = (const float*)d_in[7];
    const float* Wds  = (const float*)d_in[8];
    const float* Wdv  = (const float*)d_in[9];
    const int* esrc   = (const int*)d_in[10];
    float* out        = (float*)d_out;

    edge_kernel<<<dim3(NN / 4), dim3(256), 0, stream>>>(
        f, pos, Wqs, Wqv, Wds, Wdv, Wk1, Wv1, Wk2, Wv2, esrc, out);
}